// Round 1
// baseline (731.305 us; speedup 1.0000x reference)
//
#include <hip/hip_runtime.h>
#include <math.h>

// Problem: b=16, c=64, h*w = N = 65536, fp32.
// out[b,c,n] = sum_d A'[b,c,d] * x[b,d,n]
//   A' = gamma * softmax(min_att - att) + I   (reversed softmax == exp(min-att)/sum)
//   att[b,c,d] = sum_n x[b,c,n]*x[b,d,n]
//
// ws layout (floats): [0, 512*4096) partial Gram sums (8 MB), then 16*4096 for A'.

#define CH 64
#define NPIX 65536

// ---------------- Kernel 1: partial Gram ----------------
// grid (32, 16), block 256 (4 waves). Wave w of block bx handles chunk-stream
// k = bx*4+w: n in [k*512, (k+1)*512), 8 tiles of 64 n.
// LDS tile per wave: 64 rows x 64 floats, XOR-swizzled in float4 groups:
//   phys(c, g) = c*64 + 4*(g ^ (c&7))   -> both row-reads below are conflict-free
// Register blocking 8x8: lane(tx=lane&7, ty=lane>>3): c = tx+8m, d = ty+8p.
__global__ __launch_bounds__(256, 2) void ca_gram_kernel(
    const float* __restrict__ x, float* __restrict__ partials) {
  __shared__ float lds[4][4096];   // 64 KiB
  const int b    = blockIdx.y;
  const int wave = threadIdx.x >> 6;
  const int lane = threadIdx.x & 63;
  const int tx   = lane & 7;
  const int ty   = (lane >> 3) & 7;
  const int nblk = lane & 15;      // staging: float4 group within row
  const int r0   = lane >> 4;      // staging: row group (0..3)
  const int k    = blockIdx.x * 4 + wave;
  const float* qb = x + (size_t)b * CH * NPIX;
  float* tile = lds[wave];

  float acc[8][8];
#pragma unroll
  for (int m = 0; m < 8; ++m)
#pragma unroll
    for (int p = 0; p < 8; ++p) acc[m][p] = 0.f;

  for (int t = 0; t < 8; ++t) {
    const int n0 = k * 512 + t * 64;
    // stage 64x64 tile (each lane: 16 float4, 256B-contiguous per row group)
#pragma unroll
    for (int m = 0; m < 16; ++m) {
      const int c = r0 * 16 + m;                     // c&7 == m&7
      const float4 v = *(const float4*)(qb + (size_t)c * NPIX + n0 + nblk * 4);
      *(float4*)(tile + c * 64 + ((nblk ^ (m & 7)) << 2)) = v;
    }
    __syncthreads();
    for (int g = 0; g < 16; ++g) {       // 16 n-groups of 4
      float4 a4[8], b4[8];
#pragma unroll
      for (int m = 0; m < 8; ++m) {
        a4[m] = *(const float4*)(tile + (tx + 8 * m) * 64 + ((g ^ tx) << 2));
        b4[m] = *(const float4*)(tile + (ty + 8 * m) * 64 + ((g ^ ty) << 2));
      }
#pragma unroll
      for (int m = 0; m < 8; ++m)
#pragma unroll
        for (int p = 0; p < 8; ++p)
          acc[m][p] = fmaf(a4[m].x, b4[p].x,
                      fmaf(a4[m].y, b4[p].y,
                      fmaf(a4[m].z, b4[p].z,
                      fmaf(a4[m].w, b4[p].w, acc[m][p]))));
    }
    __syncthreads();
  }
  // dump accumulators into own tile region as plain [c][d]
#pragma unroll
  for (int m = 0; m < 8; ++m)
#pragma unroll
    for (int p = 0; p < 8; ++p)
      tile[(tx + 8 * m) * 64 + (ty + 8 * p)] = acc[m][p];
  __syncthreads();
  // cross-wave sum -> one coalesced partial per block
  float* outp = partials + (size_t)(b * 32 + blockIdx.x) * 4096;
  for (int i = threadIdx.x; i < 4096; i += 256)
    outp[i] = lds[0][i] + lds[1][i] + lds[2][i] + lds[3][i];
}

// ---------------- Kernel 2: reduce partials + reversed softmax + fold gamma/I ----
// grid (64, 16), block 64. One wave per (b, c) row; lane = d.
__global__ void ca_softmax_kernel(const float* __restrict__ partials,
                                  const float* __restrict__ gamma,
                                  float* __restrict__ Ap) {
  const int b = blockIdx.y, c = blockIdx.x, d = threadIdx.x;
  const float* p = partials + (size_t)b * 32 * 4096 + c * 64 + d;
  float s = 0.f;
#pragma unroll
  for (int kk = 0; kk < 32; ++kk) s += p[(size_t)kk * 4096];
  // reversed softmax == exp(min_row - att) / sum
  float mn = s;
#pragma unroll
  for (int off = 32; off > 0; off >>= 1) mn = fminf(mn, __shfl_down(mn, off));
  mn = __shfl(mn, 0);
  const float w = expf(mn - s);
  float sum = w;
#pragma unroll
  for (int off = 32; off > 0; off >>= 1) sum += __shfl_down(sum, off);
  sum = __shfl(sum, 0);
  const float v = gamma[0] * (w / sum) + (c == d ? 1.f : 0.f);
  Ap[((size_t)b * 64 + c) * 64 + d] = v;
}

// ---------------- Kernel 3: out[b,c,n] = sum_d A'[c,d] x[b,d,n] ----------------
// grid (256, 16), block 256; one thread per pixel n; 64 fp32 accumulators.
// A' reads are block-uniform -> scalar-cache loads; x loads/stores coalesced.
__global__ __launch_bounds__(256, 4) void ca_apply_kernel(
    const float* __restrict__ x, const float* __restrict__ Ap,
    float* __restrict__ out) {
  const int b = blockIdx.y;
  const int n = blockIdx.x * 256 + threadIdx.x;
  const float* xb = x + (size_t)b * CH * NPIX + n;
  float* ob = out + (size_t)b * CH * NPIX + n;
  const float* Ab = Ap + (size_t)b * 4096;

  float acc[64];
#pragma unroll
  for (int c = 0; c < 64; ++c) acc[c] = 0.f;

  for (int d0 = 0; d0 < 64; d0 += 4) {
    const float q0 = xb[(size_t)(d0 + 0) * NPIX];
    const float q1 = xb[(size_t)(d0 + 1) * NPIX];
    const float q2 = xb[(size_t)(d0 + 2) * NPIX];
    const float q3 = xb[(size_t)(d0 + 3) * NPIX];
#pragma unroll
    for (int c = 0; c < 64; ++c) {
      const float4 a = *(const float4*)(Ab + c * 64 + d0);   // uniform -> s_load
      acc[c] = fmaf(a.x, q0, fmaf(a.y, q1, fmaf(a.z, q2, fmaf(a.w, q3, acc[c]))));
    }
  }
#pragma unroll
  for (int c = 0; c < 64; ++c) ob[(size_t)c * NPIX] = acc[c];
}

extern "C" void kernel_launch(void* const* d_in, const int* in_sizes, int n_in,
                              void* d_out, int out_size, void* d_ws, size_t ws_size,
                              hipStream_t stream) {
  const float* x     = (const float*)d_in[0];
  const float* gamma = (const float*)d_in[1];
  float* out      = (float*)d_out;
  float* partials = (float*)d_ws;                    // 512*4096 floats = 8 MB
  float* Ap       = partials + (size_t)512 * 4096;   // 16*4096 floats

  ca_gram_kernel<<<dim3(32, 16), 256, 0, stream>>>(x, partials);
  ca_softmax_kernel<<<dim3(64, 16), 64, 0, stream>>>(partials, gamma, Ap);
  ca_apply_kernel<<<dim3(256, 16), 256, 0, stream>>>(x, Ap, out);
}

// Round 2
// 636.104 us; speedup vs baseline: 1.1497x; 1.1497x over previous
//
#include <hip/hip_runtime.h>
#include <math.h>

// b=16, c=64, N=65536 fp32.
// out[b,c,n] = sum_d A'[b,c,d] * x[b,d,n],  A' = gamma*softmax(min-att)+I,
// att = Q Q^T (Q = x reshaped [b,64,N]).
// ws floats: [0, 512*4096) gram partials (8 MB); then 16*4096 A'^T ([b][d][c]).

#define CH 64
#define NPIX 65536

// ---------------- Kernel 1: partial Gram ----------------
// grid (32,16), block 256 = 4 waves. Wave w: n-chunk k=bx*4+w (512 px, 8 tiles
// of 64). Private 64x64 LDS tile, XOR-swizzled float4 groups:
//   phys(c,g) = c*64 + 4*(g ^ (c&7))  -> both compute reads conflict-free.
// NO in-loop barriers: tile is wave-private; DS ops are in-order per wave.
// Staging software-pipelined through 16 float4 prefetch regs.
__global__ __launch_bounds__(256, 2) void ca_gram_kernel(
    const float* __restrict__ x, float* __restrict__ partials) {
  __shared__ float lds[4][4096];   // 64 KiB
  const int b    = blockIdx.y;
  const int wave = threadIdx.x >> 6;
  const int lane = threadIdx.x & 63;
  const int tx   = lane & 7;
  const int ty   = (lane >> 3) & 7;
  const int nblk = lane & 15;      // float4 group within row
  const int r0   = lane >> 4;      // row group (0..3)
  const int k    = blockIdx.x * 4 + wave;
  const float* qb = x + (size_t)b * CH * NPIX;
  float* tile = lds[wave];

  float acc[8][8];
#pragma unroll
  for (int m = 0; m < 8; ++m)
#pragma unroll
    for (int p = 0; p < 8; ++p) acc[m][p] = 0.f;

  float4 pre[16];
#pragma unroll
  for (int m = 0; m < 16; ++m) {
    const int c = r0 * 16 + m;
    pre[m] = *(const float4*)(qb + (size_t)c * NPIX + k * 512 + nblk * 4);
  }

  for (int t = 0; t < 8; ++t) {
    // write prefetched tile t (in-order DS: cannot clobber tile t-1 reads)
#pragma unroll
    for (int m = 0; m < 16; ++m) {
      const int c = r0 * 16 + m;                    // c&7 == m&7
      *(float4*)(tile + c * 64 + ((nblk ^ (m & 7)) << 2)) = pre[m];
    }
    // issue next tile's global loads; latency hides behind compute below
    if (t < 7) {
#pragma unroll
      for (int m = 0; m < 16; ++m) {
        const int c = r0 * 16 + m;
        pre[m] = *(const float4*)(qb + (size_t)c * NPIX + k * 512 + (t + 1) * 64 + nblk * 4);
      }
    }
    for (int g = 0; g < 16; ++g) {       // 16 n-groups of 4
      float4 a4[8], b4[8];
#pragma unroll
      for (int m = 0; m < 8; ++m) {
        a4[m] = *(const float4*)(tile + (tx + 8 * m) * 64 + ((g ^ tx) << 2));
        b4[m] = *(const float4*)(tile + (ty + 8 * m) * 64 + ((g ^ ty) << 2));
      }
#pragma unroll
      for (int m = 0; m < 8; ++m)
#pragma unroll
        for (int p = 0; p < 8; ++p)
          acc[m][p] = fmaf(a4[m].x, b4[p].x,
                      fmaf(a4[m].y, b4[p].y,
                      fmaf(a4[m].z, b4[p].z,
                      fmaf(a4[m].w, b4[p].w, acc[m][p]))));
    }
  }
  // dump accumulators into own tile region as plain [c][d]
#pragma unroll
  for (int m = 0; m < 8; ++m)
#pragma unroll
    for (int p = 0; p < 8; ++p)
      tile[(tx + 8 * m) * 64 + (ty + 8 * p)] = acc[m][p];
  __syncthreads();
  // cross-wave sum -> one coalesced partial per block
  float* outp = partials + (size_t)(b * 32 + blockIdx.x) * 4096;
  for (int i = threadIdx.x; i < 4096; i += 256)
    outp[i] = lds[0][i] + lds[1][i] + lds[2][i] + lds[3][i];
}

// ---------------- Kernel 2: reduce + reversed softmax -> A'^T ----------------
// grid (64,16), block 64: one wave per (b,c) row; lane = d.
// Writes A'^T[b][d][c] = gamma*softmax_row(c)[d] + (c==d).
__global__ void ca_softmax_kernel(const float* __restrict__ partials,
                                  const float* __restrict__ gamma,
                                  float* __restrict__ ApT) {
  const int b = blockIdx.y, c = blockIdx.x, d = threadIdx.x;
  const float* p = partials + (size_t)b * 32 * 4096 + c * 64 + d;
  float s = 0.f;
#pragma unroll
  for (int kk = 0; kk < 32; ++kk) s += p[(size_t)kk * 4096];
  // reversed softmax == exp(min_row - att) / sum
  float mn = s;
#pragma unroll
  for (int off = 32; off > 0; off >>= 1) mn = fminf(mn, __shfl_down(mn, off));
  mn = __shfl(mn, 0);
  const float w = expf(mn - s);
  float sum = w;
#pragma unroll
  for (int off = 32; off > 0; off >>= 1) sum += __shfl_down(sum, off);
  sum = __shfl(sum, 0);
  const float v = gamma[0] * (w / sum) + (c == d ? 1.f : 0.f);
  ApT[((size_t)b * 64 + d) * 64 + c] = v;   // transposed for apply kernel
}

// ---------------- Kernel 3: out[b,c,n] = sum_d A'[c,d] x[b,d,n] --------------
// grid (256,16), block 256 = 4 waves. Block owns 256 consecutive pixels.
// Wave w -> channels [16w,16w+16); lane -> 4 consecutive pixels.
// acc = 16 float4 (64 VGPRs). x: coalesced dwordx4. A'^T: LDS b128 broadcast.
__global__ __launch_bounds__(256, 2) void ca_apply_kernel(
    const float* __restrict__ x, const float* __restrict__ ApT,
    float* __restrict__ out) {
  __shared__ float At[4096];                 // [d][c], 16 KiB
  const int b    = blockIdx.y;
  const int tid  = threadIdx.x;
  const int wave = tid >> 6;
  const int lane = tid & 63;
  const int c0   = wave * 16;

  const float* src = ApT + (size_t)b * 4096;
#pragma unroll
  for (int i = 0; i < 4; ++i)
    ((float4*)At)[tid + 256 * i] = ((const float4*)src)[tid + 256 * i];
  __syncthreads();

  const size_t pix = (size_t)blockIdx.x * 256 + lane * 4;
  const float* xb = x + (size_t)b * CH * NPIX + pix;
  float4 acc[16];
#pragma unroll
  for (int c = 0; c < 16; ++c) acc[c] = make_float4(0.f, 0.f, 0.f, 0.f);

  for (int d0 = 0; d0 < 64; d0 += 4) {
    float4 xv[4];
#pragma unroll
    for (int j = 0; j < 4; ++j)
      xv[j] = *(const float4*)(xb + (size_t)(d0 + j) * NPIX);
#pragma unroll
    for (int j = 0; j < 4; ++j) {
#pragma unroll
      for (int q = 0; q < 4; ++q) {
        const float4 a = *(const float4*)(At + (d0 + j) * 64 + c0 + q * 4);  // broadcast
        const float av[4] = {a.x, a.y, a.z, a.w};
#pragma unroll
        for (int e = 0; e < 4; ++e) {
          float4& A4 = acc[q * 4 + e];
          A4.x = fmaf(av[e], xv[j].x, A4.x);
          A4.y = fmaf(av[e], xv[j].y, A4.y);
          A4.z = fmaf(av[e], xv[j].z, A4.z);
          A4.w = fmaf(av[e], xv[j].w, A4.w);
        }
      }
    }
  }
  float* ob = out + (size_t)b * CH * NPIX + pix;
#pragma unroll
  for (int c = 0; c < 16; ++c)
    *(float4*)(ob + (size_t)(c0 + c) * NPIX) = acc[c];
}

extern "C" void kernel_launch(void* const* d_in, const int* in_sizes, int n_in,
                              void* d_out, int out_size, void* d_ws, size_t ws_size,
                              hipStream_t stream) {
  const float* x     = (const float*)d_in[0];
  const float* gamma = (const float*)d_in[1];
  float* out      = (float*)d_out;
  float* partials = (float*)d_ws;                    // 512*4096 floats = 8 MB
  float* ApT      = partials + (size_t)512 * 4096;   // 16*4096 floats

  ca_gram_kernel<<<dim3(32, 16), 256, 0, stream>>>(x, partials);
  ca_softmax_kernel<<<dim3(64, 16), 64, 0, stream>>>(partials, gamma, ApT);
  ca_apply_kernel<<<dim3(256, 16), 256, 0, stream>>>(x, ApT, out);
}